// Round 5
// baseline (179.258 us; speedup 1.0000x reference)
//
#include <hip/hip_runtime.h>

// RBF-ANN pipeline, G-form with precomputed transposed RBF:
//   rbfT[c][i]  (i = counting-sorted node position, zero-padded)
//   G[b,c,d] = sum_i rbf[i,c] * x[order[i],d]   (in registers, per block=batch)
//   head fused: w = G(W1@Wa)+ba ; softmax ; u = attn^T G ; h = LReLU(u(W1@W2)+b2) ; LN ; out
// Kernels: memset(cnt) -> precomp -> hist -> scan -> scatter -> rbf -> gfuse

#define FMA4(A, R, V) \
    do { (A).x += (R)*(V).x; (A).y += (R)*(V).y; (A).z += (R)*(V).z; (A).w += (R)*(V).w; } while (0)

__global__ __launch_bounds__(256) void hist_k(const int* __restrict__ batch, int n, int* __restrict__ cnt) {
    for (int i = blockIdx.x * blockDim.x + threadIdx.x; i < n; i += gridDim.x * blockDim.x)
        atomicAdd(&cnt[batch[i]], 1);
}

__global__ __launch_bounds__(512) void scan_k(const int* __restrict__ cnt, int* __restrict__ offs,
                                              int* __restrict__ cursor) {
    __shared__ int s[512];
    int t = threadIdx.x;
    s[t] = cnt[t];
    __syncthreads();
    for (int o = 1; o < 512; o <<= 1) {
        int v = (t >= o) ? s[t - o] : 0;
        __syncthreads();
        s[t] += v;
        __syncthreads();
    }
    offs[t + 1] = s[t];
    if (t == 0) offs[0] = 0;
    cursor[t] = s[t] - cnt[t];
}

__global__ __launch_bounds__(256) void scatter_k(const int* __restrict__ batch, int n,
                                                 int* __restrict__ cursor, int* __restrict__ order) {
    for (int i = blockIdx.x * blockDim.x + threadIdx.x; i < n; i += gridDim.x * blockDim.x) {
        int p = atomicAdd(&cursor[batch[i]], 1);
        order[p] = i;
    }
}

// v = W1@Wa [128], M = W1@W2 [128,128]. 128 blocks x 128 threads.
__global__ __launch_bounds__(128) void precomp_k(const float* __restrict__ W1, const float* __restrict__ Wa,
                                                 const float* __restrict__ W2,
                                                 float* __restrict__ v, float* __restrict__ M) {
    __shared__ float W1s[64];
    const int i = blockIdx.x, t = threadIdx.x;
    if (t < 64) W1s[t] = W1[i * 64 + t];
    __syncthreads();
    float m = 0.f;
    #pragma unroll 8
    for (int h = 0; h < 64; ++h) m += W1s[h] * W2[h * 128 + t];
    M[i * 128 + t] = m;
    if (t == 0) {
        float s = 0.f;
        for (int h = 0; h < 64; ++h) s += W1s[h] * Wa[h];
        v[i] = s;
    }
}

// rbfT[c][i] = exp(-||pos[order[i]] - centers[c]|| / widths[c]^2), zero for i >= N.
// Block: 64 sorted positions; 256 threads: c = t&63, wave q handles 16 nodes.
__global__ __launch_bounds__(256) void rbf_k(
    const float* __restrict__ pos, const int* __restrict__ order,
    const float* __restrict__ centers, const float* __restrict__ widths,
    float* __restrict__ rbfT, int N, int Npad)
{
    __shared__ float Ts[64][65];
    const int t = threadIdx.x, c = t & 63, q = t >> 6;
    const int i0 = blockIdx.x * 64;
    const float cx = centers[3 * c], cy = centers[3 * c + 1], cz = centers[3 * c + 2];
    const float wd = widths[c];
    const float iw2 = 1.f / (wd * wd);
    #pragma unroll
    for (int jj = 0; jj < 16; ++jj) {
        int i = i0 + q * 16 + jj;
        int o = order[min(i, N - 1)];
        float px = pos[3 * o], py = pos[3 * o + 1], pz = pos[3 * o + 2];
        float dx = px - cx, dy = py - cy, dz = pz - cz;
        float val = __expf(-sqrtf(dx * dx + dy * dy + dz * dz) * iw2);
        Ts[q * 16 + jj][c] = (i < N) ? val : 0.f;
    }
    __syncthreads();
    // coalesced write: thread t writes 16 floats of row r at cols i0+16q..
    const int r = t & 63;
    float tmp[16];
    #pragma unroll
    for (int jj = 0; jj < 16; ++jj) tmp[jj] = Ts[q * 16 + jj][r];
    float* dst = rbfT + (size_t)r * Npad + i0 + q * 16;
    ((float4*)dst)[0] = make_float4(tmp[0],  tmp[1],  tmp[2],  tmp[3]);
    ((float4*)dst)[1] = make_float4(tmp[4],  tmp[5],  tmp[6],  tmp[7]);
    ((float4*)dst)[2] = make_float4(tmp[8],  tmp[9],  tmp[10], tmp[11]);
    ((float4*)dst)[3] = make_float4(tmp[12], tmp[13], tmp[14], tmp[15]);
}

// One block per batch; 512 threads = 8 waves. Wave w owns centers [8w,8w+8).
// Lane: p = lane>>3 -> center c_own = 8w+p; k = lane&7 -> d-slice [16k,16k+16).
// Accumulator: 16 floats (4 float4), statically indexed. Hot loop: 8 rbf scalar
// loads (L1 broadcast) + 32 dwordx4 x loads + 128 FMAs per 8-node chunk.
// End: G -> LDS, fused head (attention + MLP + LN + out).
__global__ __launch_bounds__(512, 4) void gfuse_k(
    const float* __restrict__ x, const int* __restrict__ order, const int* __restrict__ offs,
    const float* __restrict__ rbfT, int Npad,
    const float* __restrict__ v, const float* __restrict__ M,
    const float* __restrict__ ba, const float* __restrict__ b2,
    const float* __restrict__ gamma_, const float* __restrict__ beta_,
    const float* __restrict__ W3, const float* __restrict__ b3,
    float* __restrict__ out)
{
    __shared__ float Gs[64 * 132];
    __shared__ float vs[128];
    __shared__ float attn_s[64];
    __shared__ float us[128];
    __shared__ float red[2];

    const int t = threadIdx.x, lane = t & 63, w = t >> 6;
    const int b = blockIdx.x;
    const int p = lane >> 3, k = lane & 7;
    const int c_own = 8 * w + p;
    const int d0 = 16 * k;
    const float* rrow = rbfT + (size_t)c_own * Npad;

    float4 a0 = make_float4(0.f, 0.f, 0.f, 0.f), a1 = a0, a2 = a0, a3 = a0;

    const int start = offs[b], end = offs[b + 1];
    for (int cb = start; cb < end; cb += 64) {
        const int mm = min(64, end - cb);
        const int ov = order[cb + min(lane, mm - 1)];
        for (int sb = 0; sb < mm; sb += 8) {
            #pragma unroll
            for (int n = 0; n < 8; ++n) {
                const int i = sb + n;
                float rv = rrow[cb + i];            // over-read masked below (zero-padded array)
                rv = (i < mm) ? rv : 0.f;
                const int o = __shfl(ov, min(i, mm - 1), 64);
                const float4* xp = (const float4*)(x + (size_t)o * 128 + d0);
                float4 xv0 = xp[0], xv1 = xp[1], xv2 = xp[2], xv3 = xp[3];
                FMA4(a0, rv, xv0);
                FMA4(a1, rv, xv1);
                FMA4(a2, rv, xv2);
                FMA4(a3, rv, xv3);
            }
        }
    }

    // G tile -> LDS
    {
        float* gp = Gs + c_own * 132 + d0;
        *(float4*)(gp + 0)  = a0;
        *(float4*)(gp + 4)  = a1;
        *(float4*)(gp + 8)  = a2;
        *(float4*)(gp + 12) = a3;
    }
    if (t < 128) vs[t] = v[t];
    __syncthreads();

    // attention scores + softmax over C=64 (wave 0)
    if (t < 64) {
        float s = 0.f;
        #pragma unroll 8
        for (int d4 = 0; d4 < 32; ++d4) {
            float4 gv = *(const float4*)(Gs + t * 132 + 4 * d4);
            float4 vv = *(const float4*)(vs + 4 * d4);
            s += gv.x * vv.x + gv.y * vv.y + gv.z * vv.z + gv.w * vv.w;
        }
        s += ba[0];
        float m = s;
        #pragma unroll
        for (int o = 32; o > 0; o >>= 1) m = fmaxf(m, __shfl_xor(m, o, 64));
        float e = __expf(s - m);
        float se = e;
        #pragma unroll
        for (int o = 32; o > 0; o >>= 1) se += __shfl_xor(se, o, 64);
        attn_s[t] = e / se;
    }
    __syncthreads();

    if (t < 128) {
        float s = 0.f;
        #pragma unroll 8
        for (int c = 0; c < 64; ++c) s += attn_s[c] * Gs[c * 132 + t];
        us[t] = s;
    }
    __syncthreads();

    float hv = 0.f;
    if (t < 128) {
        float s = 0.f;
        #pragma unroll 8
        for (int d = 0; d < 128; ++d) s += us[d] * M[d * 128 + t];
        s += b2[t];
        hv = (s >= 0.f) ? s : 0.2f * s;
    }
    // LayerNorm over 128 (waves 0-1; other waves contribute zeros but hit barriers)
    float r = hv;
    #pragma unroll
    for (int o = 32; o > 0; o >>= 1) r += __shfl_xor(r, o, 64);
    if (t < 128 && (t & 63) == 0) red[t >> 6] = r;
    __syncthreads();
    float mu = (red[0] + red[1]) * (1.f / 128.f);
    float dv = (t < 128) ? (hv - mu) : 0.f;
    r = dv * dv;
    #pragma unroll
    for (int o = 32; o > 0; o >>= 1) r += __shfl_xor(r, o, 64);
    __syncthreads();
    if (t < 128 && (t & 63) == 0) red[t >> 6] = r;
    __syncthreads();
    float var = (red[0] + red[1]) * (1.f / 128.f);
    float rstd = rsqrtf(var + 1e-5f);
    float pv = 0.f;
    if (t < 128) {
        float nv = dv * rstd * gamma_[t] + beta_[t];
        pv = nv * W3[t];
    }
    r = pv;
    #pragma unroll
    for (int o = 32; o > 0; o >>= 1) r += __shfl_xor(r, o, 64);
    __syncthreads();
    if (t < 128 && (t & 63) == 0) red[t >> 6] = r;
    __syncthreads();
    if (t == 0) out[b] = red[0] + red[1] + b3[0];
}

extern "C" void kernel_launch(void* const* d_in, const int* in_sizes, int n_in,
                              void* d_out, int out_size, void* d_ws, size_t ws_size,
                              hipStream_t stream) {
    const float* x       = (const float*)d_in[0];
    const float* pos     = (const float*)d_in[1];
    const int*   batch   = (const int*)d_in[2];
    const float* centers = (const float*)d_in[3];
    const float* widths  = (const float*)d_in[4];
    const float* W1      = (const float*)d_in[5];
    const float* Wa      = (const float*)d_in[7];
    const float* ba      = (const float*)d_in[8];
    const float* W2      = (const float*)d_in[9];
    const float* b2      = (const float*)d_in[10];
    const float* gamma_  = (const float*)d_in[11];
    const float* beta_   = (const float*)d_in[12];
    const float* W3      = (const float*)d_in[13];
    const float* b3      = (const float*)d_in[14];
    float* out = (float*)d_out;

    const int N = in_sizes[1] / 3;
    const int B = out_size;
    const int Npad = (N + 127) & ~63;        // >= N+64 padding, 64-aligned

    int* wsI    = (int*)d_ws;
    int* cnt    = wsI;
    int* offs   = wsI + 512;
    int* cursor = wsI + 1026;
    int* order  = wsI + 2048;
    const int npadN = (N + 63) & ~63;
    float* v    = (float*)(wsI + 2048 + npadN);
    float* M    = v + 128;
    float* rbfT = M + 128 * 128;             // 64 * Npad floats

    hipMemsetAsync(cnt, 0, 512 * sizeof(int), stream);
    precomp_k<<<128, 128, 0, stream>>>(W1, Wa, W2, v, M);
    int blocks = (N + 255) / 256;
    hist_k<<<blocks, 256, 0, stream>>>(batch, N, cnt);
    scan_k<<<1, 512, 0, stream>>>(cnt, offs, cursor);
    scatter_k<<<blocks, 256, 0, stream>>>(batch, N, cursor, order);
    rbf_k<<<Npad / 64, 256, 0, stream>>>(pos, order, centers, widths, rbfT, N, Npad);
    gfuse_k<<<B, 512, 0, stream>>>(x, order, offs, rbfT, Npad, v, M,
                                   ba, b2, gamma_, beta_, W3, b3, out);
}

// Round 6
// 171.405 us; speedup vs baseline: 1.0458x; 1.0458x over previous
//
#include <hip/hip_runtime.h>

// RBF-ANN pipeline, G-form, sorted-streaming:
//   order = counting sort of nodes by batch; xsort/posort = x,pos permuted to sorted order.
//   G[b,c,d] = sum_i rbf(posort[i],c) * xsort[i,d]  (registers, block=batch, rbf inline)
//   head fused: w = G(W1@Wa)+ba ; softmax ; u = attn^T G ; h = LReLU(u(W1@W2)+b2) ; LN ; out
// Kernels: memset(cnt) -> precomp -> hist -> scan -> scatter -> sortx -> gfuse

#define FMA4(A, R, V) \
    do { (A).x += (R)*(V).x; (A).y += (R)*(V).y; (A).z += (R)*(V).z; (A).w += (R)*(V).w; } while (0)

__global__ __launch_bounds__(256) void hist_k(const int* __restrict__ batch, int n, int* __restrict__ cnt) {
    for (int i = blockIdx.x * blockDim.x + threadIdx.x; i < n; i += gridDim.x * blockDim.x)
        atomicAdd(&cnt[batch[i]], 1);
}

__global__ __launch_bounds__(512) void scan_k(const int* __restrict__ cnt, int* __restrict__ offs,
                                              int* __restrict__ cursor) {
    __shared__ int s[512];
    int t = threadIdx.x;
    s[t] = cnt[t];
    __syncthreads();
    for (int o = 1; o < 512; o <<= 1) {
        int v = (t >= o) ? s[t - o] : 0;
        __syncthreads();
        s[t] += v;
        __syncthreads();
    }
    offs[t + 1] = s[t];
    if (t == 0) offs[0] = 0;
    cursor[t] = s[t] - cnt[t];
}

__global__ __launch_bounds__(256) void scatter_k(const int* __restrict__ batch, int n,
                                                 int* __restrict__ cursor, int* __restrict__ order) {
    for (int i = blockIdx.x * blockDim.x + threadIdx.x; i < n; i += gridDim.x * blockDim.x) {
        int p = atomicAdd(&cursor[batch[i]], 1);
        order[p] = i;
    }
}

// v = W1@Wa [128], M = W1@W2 [128,128]. 128 blocks x 128 threads.
__global__ __launch_bounds__(128) void precomp_k(const float* __restrict__ W1, const float* __restrict__ Wa,
                                                 const float* __restrict__ W2,
                                                 float* __restrict__ v, float* __restrict__ M) {
    __shared__ float W1s[64];
    const int i = blockIdx.x, t = threadIdx.x;
    if (t < 64) W1s[t] = W1[i * 64 + t];
    __syncthreads();
    float m = 0.f;
    #pragma unroll 8
    for (int h = 0; h < 64; ++h) m += W1s[h] * W2[h * 128 + t];
    M[i * 128 + t] = m;
    if (t == 0) {
        float s = 0.f;
        for (int h = 0; h < 64; ++h) s += W1s[h] * Wa[h];
        v[i] = s;
    }
}

// Permute x and pos into sorted order. 64 nodes per block, 256 threads.
__global__ __launch_bounds__(256) void sortx_k(
    const float* __restrict__ x, const float* __restrict__ pos, const int* __restrict__ order,
    float* __restrict__ xsort, float* __restrict__ posort, int N)
{
    __shared__ int ords[64];
    const int t = threadIdx.x;
    const int i0 = blockIdx.x * 64;
    if (t < 64) ords[t] = order[min(i0 + t, N - 1)];
    __syncthreads();
    if (t < 192) {
        int r = t / 3, c = t % 3;
        posort[(size_t)(i0 + r) * 3 + c] = pos[(size_t)ords[r] * 3 + c];
    }
    #pragma unroll
    for (int j = 0; j < 8; ++j) {
        int f4 = t + 256 * j;
        int row = f4 >> 5, c4 = f4 & 31;
        float4 v = *(const float4*)(x + (size_t)ords[row] * 128 + 4 * c4);
        *(float4*)(xsort + (size_t)(i0 + row) * 128 + 4 * c4) = v;
    }
}

// One block per batch; 512 threads = 8 waves. Wave w owns centers [8w,8w+8).
// Lane: p = lane>>3 -> center c_own = 8w+p; k = lane&7 -> d-slice [16k,16k+16).
// Accumulator: 16 floats (4 float4), statically indexed. Hot loop is pure
// streaming: uniform posort loads (SMEM), affine xsort dwordx4, inline rbf,
// 128 FMA per 8-node chunk. Tail masked via cndmask on rv.
// End: G -> LDS, fused head (attention + MLP + LN + out).
__global__ __launch_bounds__(512, 2) void gfuse_k(
    const float* __restrict__ xsort, const float* __restrict__ posort,
    const int* __restrict__ offs,
    const float* __restrict__ centers, const float* __restrict__ widths,
    const float* __restrict__ v, const float* __restrict__ M,
    const float* __restrict__ ba, const float* __restrict__ b2,
    const float* __restrict__ gamma_, const float* __restrict__ beta_,
    const float* __restrict__ W3, const float* __restrict__ b3,
    float* __restrict__ out)
{
    __shared__ float Gs[64 * 132];
    __shared__ float vs[128];
    __shared__ float attn_s[64];
    __shared__ float us[128];
    __shared__ float red[2];

    const int t = threadIdx.x, lane = t & 63, w = t >> 6;
    const int b = blockIdx.x;
    const int p = lane >> 3, k = lane & 7;
    const int c_own = 8 * w + p;
    const int d0 = 16 * k;

    const float cx = centers[3 * c_own], cy = centers[3 * c_own + 1], cz = centers[3 * c_own + 2];
    const float wd = widths[c_own];
    const float niw2 = -1.f / (wd * wd);

    float4 a0 = make_float4(0.f, 0.f, 0.f, 0.f), a1 = a0, a2 = a0, a3 = a0;

    const int start = offs[b], end = offs[b + 1];
    for (int i0 = start; i0 < end; i0 += 8) {
        #pragma unroll
        for (int n = 0; n < 8; ++n) {
            const int i = i0 + n;
            const float px = posort[3 * i], py = posort[3 * i + 1], pz = posort[3 * i + 2];
            const float dx = px - cx, dy = py - cy, dz = pz - cz;
            float rv = __expf(sqrtf(dx * dx + dy * dy + dz * dz) * niw2);
            rv = (i < end) ? rv : 0.f;
            const float4* xp = (const float4*)(xsort + (size_t)i * 128 + d0);
            float4 xv0 = xp[0], xv1 = xp[1], xv2 = xp[2], xv3 = xp[3];
            FMA4(a0, rv, xv0);
            FMA4(a1, rv, xv1);
            FMA4(a2, rv, xv2);
            FMA4(a3, rv, xv3);
        }
    }

    // G tile -> LDS
    {
        float* gp = Gs + c_own * 132 + d0;
        *(float4*)(gp + 0)  = a0;
        *(float4*)(gp + 4)  = a1;
        *(float4*)(gp + 8)  = a2;
        *(float4*)(gp + 12) = a3;
    }
    if (t < 128) vs[t] = v[t];
    __syncthreads();

    // attention scores + softmax over C=64 (wave 0)
    if (t < 64) {
        float s = 0.f;
        #pragma unroll 8
        for (int d4 = 0; d4 < 32; ++d4) {
            float4 gv = *(const float4*)(Gs + t * 132 + 4 * d4);
            float4 vv = *(const float4*)(vs + 4 * d4);
            s += gv.x * vv.x + gv.y * vv.y + gv.z * vv.z + gv.w * vv.w;
        }
        s += ba[0];
        float m = s;
        #pragma unroll
        for (int o = 32; o > 0; o >>= 1) m = fmaxf(m, __shfl_xor(m, o, 64));
        float e = __expf(s - m);
        float se = e;
        #pragma unroll
        for (int o = 32; o > 0; o >>= 1) se += __shfl_xor(se, o, 64);
        attn_s[t] = e / se;
    }
    __syncthreads();

    if (t < 128) {
        float s = 0.f;
        #pragma unroll 8
        for (int c = 0; c < 64; ++c) s += attn_s[c] * Gs[c * 132 + t];
        us[t] = s;
    }
    __syncthreads();

    float hv = 0.f;
    if (t < 128) {
        float s = 0.f;
        #pragma unroll 8
        for (int d = 0; d < 128; ++d) s += us[d] * M[d * 128 + t];
        s += b2[t];
        hv = (s >= 0.f) ? s : 0.2f * s;
    }
    // LayerNorm over 128 (waves 0-1; other waves contribute zeros but hit barriers)
    float r = hv;
    #pragma unroll
    for (int o = 32; o > 0; o >>= 1) r += __shfl_xor(r, o, 64);
    if (t < 128 && (t & 63) == 0) red[t >> 6] = r;
    __syncthreads();
    float mu = (red[0] + red[1]) * (1.f / 128.f);
    float dv = (t < 128) ? (hv - mu) : 0.f;
    r = dv * dv;
    #pragma unroll
    for (int o = 32; o > 0; o >>= 1) r += __shfl_xor(r, o, 64);
    __syncthreads();
    if (t < 128 && (t & 63) == 0) red[t >> 6] = r;
    __syncthreads();
    float var = (red[0] + red[1]) * (1.f / 128.f);
    float rstd = rsqrtf(var + 1e-5f);
    float pv = 0.f;
    if (t < 128) {
        float nv = dv * rstd * gamma_[t] + beta_[t];
        pv = nv * W3[t];
    }
    r = pv;
    #pragma unroll
    for (int o = 32; o > 0; o >>= 1) r += __shfl_xor(r, o, 64);
    __syncthreads();
    if (t < 128 && (t & 63) == 0) red[t >> 6] = r;
    __syncthreads();
    if (t == 0) out[b] = red[0] + red[1] + b3[0];
}

extern "C" void kernel_launch(void* const* d_in, const int* in_sizes, int n_in,
                              void* d_out, int out_size, void* d_ws, size_t ws_size,
                              hipStream_t stream) {
    const float* x       = (const float*)d_in[0];
    const float* pos     = (const float*)d_in[1];
    const int*   batch   = (const int*)d_in[2];
    const float* centers = (const float*)d_in[3];
    const float* widths  = (const float*)d_in[4];
    const float* W1      = (const float*)d_in[5];
    const float* Wa      = (const float*)d_in[7];
    const float* ba      = (const float*)d_in[8];
    const float* W2      = (const float*)d_in[9];
    const float* b2      = (const float*)d_in[10];
    const float* gamma_  = (const float*)d_in[11];
    const float* beta_   = (const float*)d_in[12];
    const float* W3      = (const float*)d_in[13];
    const float* b3      = (const float*)d_in[14];
    float* out = (float*)d_out;

    const int N = in_sizes[1] / 3;
    const int B = out_size;
    const int Npad = (N + 127) & ~63;        // >= N+64 padding, 64-aligned

    int*   wsI    = (int*)d_ws;
    int*   cnt    = wsI;
    int*   offs   = wsI + 512;
    int*   cursor = wsI + 1026;
    int*   order  = wsI + 2048;
    float* xsort  = (float*)(wsI + 2048 + Npad);
    float* posort = xsort + (size_t)Npad * 128;
    float* v      = posort + (size_t)Npad * 3;
    float* M      = v + 128;

    hipMemsetAsync(cnt, 0, 512 * sizeof(int), stream);
    precomp_k<<<128, 128, 0, stream>>>(W1, Wa, W2, v, M);
    int blocks = (N + 255) / 256;
    hist_k<<<blocks, 256, 0, stream>>>(batch, N, cnt);
    scan_k<<<1, 512, 0, stream>>>(cnt, offs, cursor);
    scatter_k<<<blocks, 256, 0, stream>>>(batch, N, cursor, order);
    sortx_k<<<Npad / 64, 256, 0, stream>>>(x, pos, order, xsort, posort, N);
    gfuse_k<<<B, 512, 0, stream>>>(xsort, posort, offs, centers, widths, v, M,
                                   ba, b2, gamma_, beta_, W3, b3, out);
}